// Round 1
// baseline (4497.504 us; speedup 1.0000x reference)
//
#include <hip/hip_runtime.h>
#include <math.h>

#define NTOK 4096
#define C1 64
#define C2 256
#define CF 256
#define NH 8
#define HD 32
#define CFF 1024
#define EPSF 1e-5f

// out[n*CF+f] = sum_c in[c*NTOK+n] * W[f*Cin+c]
// in is channel-major (C, N); W is (CF, Cin) row-major.
template<int Cin>
__global__ __launch_bounds__(256) void proj_kernel(const float* __restrict__ in,
                                                   const float* __restrict__ W,
                                                   float* __restrict__ out) {
    const int n = blockIdx.x;
    const int f = threadIdx.x;
    const float* ip = in + n;          // wave-uniform base + c*NTOK (scalar loads)
    const float* wp = W + f * Cin;
    float acc = 0.f;
#pragma unroll 8
    for (int c = 0; c < Cin; ++c) acc = fmaf(ip[(size_t)c * NTOK], wp[c], acc);
    out[(size_t)n * CF + f] = acc;
}

// One block per (head h, query n). Full score row in LDS, 2-pass softmax, PV.
__global__ __launch_bounds__(256) void attn_kernel(const float* __restrict__ Q,
                                                   const float* __restrict__ K,
                                                   const float* __restrict__ V,
                                                   float* __restrict__ out) {
    __shared__ float sc[NTOK];   // 16 KiB score row
    __shared__ float qs[HD];
    __shared__ float red[256];
    __shared__ float pacc[256];  // 8 groups x 32 d

    const int row = blockIdx.x;
    const int n = row & (NTOK - 1);
    const int h = row >> 12;
    const int tid = threadIdx.x;

    if (tid < HD) qs[tid] = Q[(size_t)n * CF + h * HD + tid];
    __syncthreads();

    float qr[HD];
#pragma unroll
    for (int d = 0; d < HD; ++d) qr[d] = qs[d];

    const float scale = 0.17677669529663687f;  // 32^-0.5
    float lmax = -INFINITY;
    for (int m = tid; m < NTOK; m += 256) {
        const float4* kp = (const float4*)(K + (size_t)m * CF + h * HD);
        float s = 0.f;
#pragma unroll
        for (int d4 = 0; d4 < HD / 4; ++d4) {
            float4 k4 = kp[d4];
            s = fmaf(qr[4 * d4 + 0], k4.x, s);
            s = fmaf(qr[4 * d4 + 1], k4.y, s);
            s = fmaf(qr[4 * d4 + 2], k4.z, s);
            s = fmaf(qr[4 * d4 + 3], k4.w, s);
        }
        s *= scale;
        sc[m] = s;
        lmax = fmaxf(lmax, s);
    }
    red[tid] = lmax;
    __syncthreads();
#pragma unroll
    for (int off = 128; off > 0; off >>= 1) {
        if (tid < off) red[tid] = fmaxf(red[tid], red[tid + off]);
        __syncthreads();
    }
    const float gmax = red[0];
    __syncthreads();

    float lsum = 0.f;
    for (int m = tid; m < NTOK; m += 256) {
        float e = __expf(sc[m] - gmax);
        sc[m] = e;
        lsum += e;
    }
    red[tid] = lsum;
    __syncthreads();
#pragma unroll
    for (int off = 128; off > 0; off >>= 1) {
        if (tid < off) red[tid] += red[tid + off];
        __syncthreads();
    }
    const float inv = 1.f / red[0];
    __syncthreads();

    // PV: thread t handles d = t&31, m-chunk g = t>>5 (512 m's each)
    const int d = tid & (HD - 1);
    const int g = tid >> 5;
    const float* vp = V + h * HD + d;
    float acc = 0.f;
    const int m0 = g * 512;
    for (int m = m0; m < m0 + 512; ++m) acc = fmaf(sc[m], vp[(size_t)m * CF], acc);
    pacc[tid] = acc;
    __syncthreads();
    if (tid < 128) pacc[tid] += pacc[tid + 128];
    __syncthreads();
    if (tid < 64) pacc[tid] += pacc[tid + 64];
    __syncthreads();
    if (tid < 32) {
        float r = pacc[tid] + pacc[tid + 32];
        out[(size_t)n * CF + h * HD + tid] = r * inv;
    }
}

// y[n*CF+f] = sum_g ao[n][g]*Wo[f][g] + sum_c tok_l[n][c]*Wres[f][c]
__global__ __launch_bounds__(256) void outproj_kernel(const float* __restrict__ ao,
                                                      const float* __restrict__ Wo,
                                                      const float* __restrict__ Fl,
                                                      const float* __restrict__ Wres,
                                                      float* __restrict__ y) {
    __shared__ float as[CF];
    const int n = blockIdx.x;
    const int f = threadIdx.x;
    as[f] = ao[(size_t)n * CF + f];
    __syncthreads();
    float acc = 0.f;
    const float* wo = Wo + (size_t)f * CF;
#pragma unroll 8
    for (int g = 0; g < CF; ++g) acc = fmaf(as[g], wo[g], acc);
    const float* wr = Wres + (size_t)f * C1;
    const float* fl = Fl + n;
#pragma unroll 8
    for (int c = 0; c < C1; ++c) acc = fmaf(fl[(size_t)c * NTOK], wr[c], acc);
    y[(size_t)n * CF + f] = acc;
}

template<bool TRANSPOSE>
__global__ __launch_bounds__(256) void ln_kernel(const float* __restrict__ y,
                                                 const float* __restrict__ gam,
                                                 const float* __restrict__ bet,
                                                 float* __restrict__ x) {
    __shared__ float red[256];
    const int n = blockIdx.x;
    const int f = threadIdx.x;
    const float v = y[(size_t)n * CF + f];
    red[f] = v;
    __syncthreads();
#pragma unroll
    for (int off = 128; off > 0; off >>= 1) {
        if (f < off) red[f] += red[f + off];
        __syncthreads();
    }
    const float mean = red[0] * (1.f / CF);
    __syncthreads();
    const float d = v - mean;
    red[f] = d * d;
    __syncthreads();
#pragma unroll
    for (int off = 128; off > 0; off >>= 1) {
        if (f < off) red[f] += red[f + off];
        __syncthreads();
    }
    const float rstd = rsqrtf(red[0] * (1.f / CF) + EPSF);
    const float r = d * rstd * gam[f] + bet[f];
    if (TRANSPOSE) x[(size_t)f * NTOK + n] = r;
    else x[(size_t)n * CF + f] = r;
}

// h[n][j] = relu(sum_f x[n][f]*W1[j][f] + b1[j]), j in [0,1024)
__global__ __launch_bounds__(256) void ffn1_kernel(const float* __restrict__ x,
                                                   const float* __restrict__ W1,
                                                   const float* __restrict__ b1,
                                                   float* __restrict__ h) {
    __shared__ float xs[CF];
    const int n = blockIdx.x;
    const int tid = threadIdx.x;
    xs[tid] = x[(size_t)n * CF + tid];
    __syncthreads();
#pragma unroll
    for (int jj = 0; jj < 4; ++jj) {
        const int j = jj * 256 + tid;
        const float* w = W1 + (size_t)j * CF;
        float acc = b1[j];
#pragma unroll 8
        for (int f = 0; f < CF; ++f) acc = fmaf(xs[f], w[f], acc);
        h[(size_t)n * CFF + j] = fmaxf(acc, 0.f);
    }
}

// y[n][f] = x[n][f] + b2[f] + sum_j h[n][j]*W2[f][j]
__global__ __launch_bounds__(256) void ffn2_kernel(const float* __restrict__ hbuf,
                                                   const float* __restrict__ W2,
                                                   const float* __restrict__ b2,
                                                   const float* __restrict__ x,
                                                   float* __restrict__ y) {
    __shared__ float hs[CFF];  // 4 KiB
    const int n = blockIdx.x;
    const int f = threadIdx.x;
#pragma unroll
    for (int k = 0; k < 4; ++k) hs[k * 256 + f] = hbuf[(size_t)n * CFF + k * 256 + f];
    __syncthreads();
    float acc = b2[f] + x[(size_t)n * CF + f];
    const float* w = W2 + (size_t)f * CFF;
#pragma unroll 8
    for (int j = 0; j < CFF; ++j) acc = fmaf(hs[j], w[j], acc);
    y[(size_t)n * CF + f] = acc;
}

extern "C" void kernel_launch(void* const* d_in, const int* in_sizes, int n_in,
                              void* d_out, int out_size, void* d_ws, size_t ws_size,
                              hipStream_t stream) {
    const float* F_lidar = (const float*)d_in[0];
    const float* F_cam   = (const float*)d_in[1];
    const float* Wq      = (const float*)d_in[2];
    const float* Wk      = (const float*)d_in[3];
    const float* Wv      = (const float*)d_in[4];
    const float* Wo      = (const float*)d_in[5];
    const float* Wres    = (const float*)d_in[6];
    const float* ln1_g   = (const float*)d_in[7];
    const float* ln1_b   = (const float*)d_in[8];
    const float* ln2_g   = (const float*)d_in[9];
    const float* ln2_b   = (const float*)d_in[10];
    const float* W1      = (const float*)d_in[11];
    const float* b1      = (const float*)d_in[12];
    const float* W2      = (const float*)d_in[13];
    const float* b2      = (const float*)d_in[14];
    float* out = (float*)d_out;
    float* ws  = (float*)d_ws;

    const size_t NCF = (size_t)NTOK * CF;  // 1,048,576 floats = 4 MiB
    float* Q  = ws;                        // [0, 1NCF)
    float* K  = ws + 1 * NCF;              // [1, 2)
    float* V  = ws + 2 * NCF;              // [2, 3)
    float* AO = ws + 3 * NCF;              // [3, 4)
    float* Y1 = ws + 4 * NCF;              // [4, 5)
    float* X  = ws + 5 * NCF;              // [5, 6)
    float* Hb = ws;                        // [0, 4NCF) reuses Q/K/V/AO (dead)
    float* Y2 = ws + 4 * NCF;              // reuses Y1 (dead)
    // total ws use: 6*NCF*4 = 24 MiB

    proj_kernel<C1><<<NTOK, 256, 0, stream>>>(F_lidar, Wq, Q);
    proj_kernel<C2><<<NTOK, 256, 0, stream>>>(F_cam, Wk, K);
    proj_kernel<C2><<<NTOK, 256, 0, stream>>>(F_cam, Wv, V);
    attn_kernel<<<NTOK * NH, 256, 0, stream>>>(Q, K, V, AO);
    outproj_kernel<<<NTOK, 256, 0, stream>>>(AO, Wo, F_lidar, Wres, Y1);
    ln_kernel<false><<<NTOK, 256, 0, stream>>>(Y1, ln1_g, ln1_b, X);
    ffn1_kernel<<<NTOK, 256, 0, stream>>>(X, W1, b1, Hb);
    ffn2_kernel<<<NTOK, 256, 0, stream>>>(Hb, W2, b2, X, Y2);
    ln_kernel<true><<<NTOK, 256, 0, stream>>>(Y2, ln2_g, ln2_b, out);
}

// Round 2
// 1711.826 us; speedup vs baseline: 2.6273x; 2.6273x over previous
//
#include <hip/hip_runtime.h>
#include <math.h>

#define NTOK 4096
#define C1 64
#define C2 256
#define CF 256
#define NH 8
#define HD 32
#define CFF 1024
#define EPSF 1e-5f

using f32x4  = __attribute__((ext_vector_type(4))) float;
using bf16x8 = __attribute__((ext_vector_type(8))) short;

__device__ inline unsigned short f2bf(float x) {
    union { float f; unsigned int u; } v; v.f = x;
    unsigned int r = (v.u + 0x7FFFu + ((v.u >> 16) & 1u)) >> 16;
    return (unsigned short)r;
}

// ---------- projections ----------
// Token-major bf16 out: out[n*CF+f] = bf16( sum_c in[c*NTOK+n] * W[f*Cin+c] )
template<int Cin>
__global__ __launch_bounds__(256) void proj_bf16_kernel(const float* __restrict__ in,
                                                        const float* __restrict__ W,
                                                        unsigned short* __restrict__ out) {
    const int n = blockIdx.x;
    const int f = threadIdx.x;
    const float* ip = in + n;
    const float* wp = W + (size_t)f * Cin;
    float acc = 0.f;
#pragma unroll 8
    for (int c = 0; c < Cin; ++c) acc = fmaf(ip[(size_t)c * NTOK], wp[c], acc);
    out[(size_t)n * CF + f] = f2bf(acc);
}

// Channel-major bf16 out (V^T): out[f*NTOK+n] = bf16( sum_c in[c*NTOK+n] * W[f*C2+c] )
__global__ __launch_bounds__(256) void proj_vt_kernel(const float* __restrict__ in,
                                                      const float* __restrict__ W,
                                                      unsigned short* __restrict__ out) {
    const int f = blockIdx.x;
    const int n = blockIdx.y * 256 + threadIdx.x;
    const float* wp = W + (size_t)f * C2;
    float acc = 0.f;
#pragma unroll 8
    for (int c = 0; c < C2; ++c) acc = fmaf(in[(size_t)c * NTOK + n], wp[c], acc);
    out[(size_t)f * NTOK + n] = f2bf(acc);
}

// ---------- flash attention (bf16 MFMA) ----------
// Qb,Kb: bf16 [n][CF] token-major. Vt: bf16 [CF][n] channel-major. AO: fp32 [n][CF].
// Block = 4 waves; wave w handles 16 query rows. Grid = NH * (NTOK/64).
__global__ __launch_bounds__(256) void fattn_kernel(const unsigned short* __restrict__ Qb,
                                                    const unsigned short* __restrict__ Kb,
                                                    const unsigned short* __restrict__ Vt,
                                                    float* __restrict__ AO) {
    __shared__ unsigned short plds[4][16 * 64];  // 2 KB per wave, XOR-swizzled P tile

    const int tid  = threadIdx.x;
    const int wid  = tid >> 6;
    const int lane = tid & 63;
    const int g    = lane >> 4;   // k-group 0..3
    const int r    = lane & 15;   // row/col-in-tile 0..15
    const int h    = blockIdx.x >> 6;
    const int n0   = ((blockIdx.x & 63) << 6) + (wid << 4);

    unsigned short* pw = plds[wid];
    const float scale = 0.17677669529663687f;  // 32^-0.5

    // Q fragment: A[row=r][k=8g+j]
    const bf16x8 qf = *(const bf16x8*)(Qb + ((size_t)(n0 + r) << 8) + h * HD + (g << 3));

    f32x4 acc[2] = {{0.f, 0.f, 0.f, 0.f}, {0.f, 0.f, 0.f, 0.f}};
    float m_run[4], l_run[4];
#pragma unroll
    for (int q = 0; q < 4; ++q) { m_run[q] = -1e30f; l_run[q] = 0.f; }

    for (int m0 = 0; m0 < NTOK; m0 += 64) {
        // ---- S = Q K^T for 4 col-tiles of 16 keys ----
        f32x4 s[4];
#pragma unroll
        for (int t = 0; t < 4; ++t) {
            const bf16x8 kf = *(const bf16x8*)(Kb + ((size_t)(m0 + (t << 4) + r) << 8) + h * HD + (g << 3));
            s[t] = __builtin_amdgcn_mfma_f32_16x16x32_bf16(qf, kf, (f32x4){0.f, 0.f, 0.f, 0.f}, 0, 0, 0);
        }
        // ---- online softmax: lane holds queries 4g..4g+3 (reg), keys r+16t ----
#pragma unroll
        for (int q = 0; q < 4; ++q) {
            float mt = fmaxf(fmaxf(s[0][q], s[1][q]), fmaxf(s[2][q], s[3][q])) * scale;
            mt = fmaxf(mt, __shfl_xor(mt, 1));
            mt = fmaxf(mt, __shfl_xor(mt, 2));
            mt = fmaxf(mt, __shfl_xor(mt, 4));
            mt = fmaxf(mt, __shfl_xor(mt, 8));
            const float mn  = fmaxf(m_run[q], mt);
            const float scl = __expf(m_run[q] - mn);
            m_run[q] = mn;
            float rs = 0.f;
#pragma unroll
            for (int t = 0; t < 4; ++t) {
                const float p = __expf(fmaf(s[t][q], scale, -mn));
                s[t][q] = p;
                rs += p;
            }
            rs += __shfl_xor(rs, 1);
            rs += __shfl_xor(rs, 2);
            rs += __shfl_xor(rs, 4);
            rs += __shfl_xor(rs, 8);
            l_run[q] = l_run[q] * scl + rs;
            acc[0][q] *= scl;
            acc[1][q] *= scl;
        }
        // ---- write P to per-wave LDS, bf16, XOR-swizzled ----
#pragma unroll
        for (int t = 0; t < 4; ++t) {
#pragma unroll
            for (int q = 0; q < 4; ++q) {
                const int row = (g << 2) + q;                 // query row 0..15
                const int bir = (r << 1) + (t << 5);          // byte-in-row (key*2)
                *(unsigned short*)((char*)pw + (row << 7) + (bir ^ ((row & 7) << 4))) = f2bf(s[t][q]);
            }
        }
        // ---- PV: O += P(16x64) * V(64x32) ----
#pragma unroll
        for (int mc = 0; mc < 2; ++mc) {
            const int bir = (g << 4) + (mc << 6);
            const bf16x8 pf = *(const bf16x8*)((char*)pw + (r << 7) + (bir ^ ((r & 7) << 4)));
#pragma unroll
            for (int dd = 0; dd < 2; ++dd) {
                const bf16x8 vf = *(const bf16x8*)(Vt + ((size_t)(h * HD + (dd << 4) + r) << 12) + m0 + (mc << 5) + (g << 3));
                acc[dd] = __builtin_amdgcn_mfma_f32_16x16x32_bf16(pf, vf, acc[dd], 0, 0, 0);
            }
        }
    }
    // ---- epilogue: divide by row-sum, write AO[n][CF] fp32 ----
#pragma unroll
    for (int q = 0; q < 4; ++q) {
        const float inv = 1.f / l_run[q];
        const size_t row = (size_t)(n0 + (g << 2) + q) << 8;
        AO[row + h * HD + r]      = acc[0][q] * inv;
        AO[row + h * HD + 16 + r] = acc[1][q] * inv;
    }
}

// ---------- out-proj + residual-proj ----------
__global__ __launch_bounds__(256) void outproj_kernel(const float* __restrict__ ao,
                                                      const float* __restrict__ Wo,
                                                      const float* __restrict__ Fl,
                                                      const float* __restrict__ Wres,
                                                      float* __restrict__ y) {
    __shared__ float as[CF];
    const int n = blockIdx.x;
    const int f = threadIdx.x;
    as[f] = ao[(size_t)n * CF + f];
    __syncthreads();
    float acc = 0.f;
    const float* wo = Wo + (size_t)f * CF;
#pragma unroll 8
    for (int c = 0; c < CF; ++c) acc = fmaf(as[c], wo[c], acc);
    const float* wr = Wres + (size_t)f * C1;
    const float* fl = Fl + n;
#pragma unroll 8
    for (int c = 0; c < C1; ++c) acc = fmaf(fl[(size_t)c * NTOK], wr[c], acc);
    y[(size_t)n * CF + f] = acc;
}

template<bool TRANSPOSE>
__global__ __launch_bounds__(256) void ln_kernel(const float* __restrict__ y,
                                                 const float* __restrict__ gam,
                                                 const float* __restrict__ bet,
                                                 float* __restrict__ x) {
    __shared__ float red[256];
    const int n = blockIdx.x;
    const int f = threadIdx.x;
    const float v = y[(size_t)n * CF + f];
    red[f] = v;
    __syncthreads();
#pragma unroll
    for (int off = 128; off > 0; off >>= 1) {
        if (f < off) red[f] += red[f + off];
        __syncthreads();
    }
    const float mean = red[0] * (1.f / CF);
    __syncthreads();
    const float d = v - mean;
    red[f] = d * d;
    __syncthreads();
#pragma unroll
    for (int off = 128; off > 0; off >>= 1) {
        if (f < off) red[f] += red[f + off];
        __syncthreads();
    }
    const float rstd = rsqrtf(red[0] * (1.f / CF) + EPSF);
    const float rr = d * rstd * gam[f] + bet[f];
    if (TRANSPOSE) x[(size_t)f * NTOK + n] = rr;
    else x[(size_t)n * CF + f] = rr;
}

__global__ __launch_bounds__(256) void ffn1_kernel(const float* __restrict__ x,
                                                   const float* __restrict__ W1,
                                                   const float* __restrict__ b1,
                                                   float* __restrict__ h) {
    __shared__ float xs[CF];
    const int n = blockIdx.x;
    const int tid = threadIdx.x;
    xs[tid] = x[(size_t)n * CF + tid];
    __syncthreads();
#pragma unroll
    for (int jj = 0; jj < 4; ++jj) {
        const int j = jj * 256 + tid;
        const float* w = W1 + (size_t)j * CF;
        float acc = b1[j];
#pragma unroll 8
        for (int f = 0; f < CF; ++f) acc = fmaf(xs[f], w[f], acc);
        h[(size_t)n * CFF + j] = fmaxf(acc, 0.f);
    }
}

__global__ __launch_bounds__(256) void ffn2_kernel(const float* __restrict__ hbuf,
                                                   const float* __restrict__ W2,
                                                   const float* __restrict__ b2,
                                                   const float* __restrict__ x,
                                                   float* __restrict__ y) {
    __shared__ float hs[CFF];
    const int n = blockIdx.x;
    const int f = threadIdx.x;
#pragma unroll
    for (int k = 0; k < 4; ++k) hs[k * 256 + f] = hbuf[(size_t)n * CFF + k * 256 + f];
    __syncthreads();
    float acc = b2[f] + x[(size_t)n * CF + f];
    const float* w = W2 + (size_t)f * CFF;
#pragma unroll 8
    for (int j = 0; j < CFF; ++j) acc = fmaf(hs[j], w[j], acc);
    y[(size_t)n * CF + f] = acc;
}

extern "C" void kernel_launch(void* const* d_in, const int* in_sizes, int n_in,
                              void* d_out, int out_size, void* d_ws, size_t ws_size,
                              hipStream_t stream) {
    const float* F_lidar = (const float*)d_in[0];
    const float* F_cam   = (const float*)d_in[1];
    const float* Wq      = (const float*)d_in[2];
    const float* Wk      = (const float*)d_in[3];
    const float* Wv      = (const float*)d_in[4];
    const float* Wo      = (const float*)d_in[5];
    const float* Wres    = (const float*)d_in[6];
    const float* ln1_g   = (const float*)d_in[7];
    const float* ln1_b   = (const float*)d_in[8];
    const float* ln2_g   = (const float*)d_in[9];
    const float* ln2_b   = (const float*)d_in[10];
    const float* W1      = (const float*)d_in[11];
    const float* b1      = (const float*)d_in[12];
    const float* W2      = (const float*)d_in[13];
    const float* b2      = (const float*)d_in[14];
    float* out = (float*)d_out;
    char* ws = (char*)d_ws;

    const size_t MB = 1024 * 1024;
    unsigned short* Qb = (unsigned short*)(ws + 0 * MB);    // 2 MB  bf16 [n][CF]
    unsigned short* Kb = (unsigned short*)(ws + 2 * MB);    // 2 MB  bf16 [n][CF]
    unsigned short* Vt = (unsigned short*)(ws + 4 * MB);    // 2 MB  bf16 [CF][n]
    float* AO = (float*)(ws + 6 * MB);                      // 4 MB  fp32 [n][CF]
    float* Y1 = (float*)(ws + 10 * MB);                     // 4 MB
    float* Hb = (float*)(ws + 0 * MB);                      // 16 MB (reuses Qb/Kb/Vt/AO/Y1, all dead)
    float* X  = (float*)(ws + 16 * MB);                     // 4 MB
    float* Y2 = (float*)(ws + 20 * MB);                     // 4 MB   total 24 MB

    proj_bf16_kernel<C1><<<NTOK, 256, 0, stream>>>(F_lidar, Wq, Qb);
    proj_bf16_kernel<C2><<<NTOK, 256, 0, stream>>>(F_cam, Wk, Kb);
    proj_vt_kernel<<<dim3(CF, NTOK / 256), 256, 0, stream>>>(F_cam, Wv, Vt);
    fattn_kernel<<<NH * (NTOK / 64), 256, 0, stream>>>(Qb, Kb, Vt, AO);
    outproj_kernel<<<NTOK, 256, 0, stream>>>(AO, Wo, F_lidar, Wres, Y1);
    ln_kernel<false><<<NTOK, 256, 0, stream>>>(Y1, ln1_g, ln1_b, X);
    ffn1_kernel<<<NTOK, 256, 0, stream>>>(X, W1, b1, Hb);
    ffn2_kernel<<<NTOK, 256, 0, stream>>>(Hb, W2, b2, X, (float*)Y2);
    ln_kernel<true><<<NTOK, 256, 0, stream>>>(Y2, ln2_g, ln2_b, out);
}

// Round 3
// 263.181 us; speedup vs baseline: 17.0890x; 6.5044x over previous
//
#include <hip/hip_runtime.h>
#include <math.h>

#define NTOK 4096
#define C1 64
#define C2 256
#define CF 256
#define NH 8
#define HD 32
#define CFF 1024
#define EPSF 1e-5f

using f32x4  = __attribute__((ext_vector_type(4))) float;
using bf16x8 = __attribute__((ext_vector_type(8))) short;
typedef unsigned short ushort_t;

__device__ inline unsigned short f2bf(float x) {
    union { float f; unsigned int u; } v; v.f = x;
    unsigned int r = (v.u + 0x7FFFu + ((v.u >> 16) & 1u)) >> 16;
    return (unsigned short)r;
}

__device__ inline float rsum16(float s) {
    s += __shfl_xor(s, 1);
    s += __shfl_xor(s, 2);
    s += __shfl_xor(s, 4);
    s += __shfl_xor(s, 8);
    return s;
}

// ---------- weight convert fp32 -> bf16 (all 7 matrices, one launch) ----------
__global__ __launch_bounds__(256) void convert_weights_kernel(
    const float* __restrict__ Wq, const float* __restrict__ Wk,
    const float* __restrict__ Wv, const float* __restrict__ Wo,
    const float* __restrict__ Wres, const float* __restrict__ W1,
    const float* __restrict__ W2,
    ushort_t* oWq, ushort_t* oWk, ushort_t* oWv, ushort_t* oWo,
    ushort_t* oWres, ushort_t* oW1, ushort_t* oW2) {
    const int b = blockIdx.x;
    const float* src; ushort_t* dst; int base;
    if      (b < 16)  { src = Wq;   dst = oWq;   base = b; }
    else if (b < 80)  { src = Wk;   dst = oWk;   base = b - 16; }
    else if (b < 144) { src = Wv;   dst = oWv;   base = b - 80; }
    else if (b < 208) { src = Wo;   dst = oWo;   base = b - 144; }
    else if (b < 224) { src = Wres; dst = oWres; base = b - 208; }
    else if (b < 480) { src = W1;   dst = oW1;   base = b - 224; }
    else              { src = W2;   dst = oW2;   base = b - 480; }
    const size_t i = (size_t)base * 1024 + (size_t)threadIdx.x * 4;
    const float4 v = *(const float4*)(src + i);
    ushort_t o0 = f2bf(v.x), o1 = f2bf(v.y), o2 = f2bf(v.z), o3 = f2bf(v.w);
    ushort_t* d = dst + i;
    d[0] = o0; d[1] = o1; d[2] = o2; d[3] = o3;
}

// ---------- transpose fp32 [C][NTOK] -> bf16 [NTOK][C] ----------
template<int C>
__global__ __launch_bounds__(256) void tr_f32_kernel(const float* __restrict__ src,
                                                     ushort_t* __restrict__ dst) {
    __shared__ float t[32][33];
    const int c0 = blockIdx.x * 32, n0 = blockIdx.y * 32;
    const int tx = threadIdx.x & 31, ty = threadIdx.x >> 5;
#pragma unroll
    for (int i = 0; i < 32; i += 8) t[ty + i][tx] = src[(size_t)(c0 + ty + i) * NTOK + n0 + tx];
    __syncthreads();
#pragma unroll
    for (int i = 0; i < 32; i += 8) dst[(size_t)(n0 + ty + i) * C + c0 + tx] = f2bf(t[tx][ty + i]);
}

// ---------- transpose bf16 [NTOK][CF] -> bf16 [CF][NTOK] ----------
__global__ __launch_bounds__(256) void tr_bf16_kernel(const ushort_t* __restrict__ src,
                                                      ushort_t* __restrict__ dst) {
    __shared__ ushort_t t[32][34];
    const int n0 = blockIdx.x * 32, f0 = blockIdx.y * 32;
    const int tx = threadIdx.x & 31, ty = threadIdx.x >> 5;
#pragma unroll
    for (int i = 0; i < 32; i += 8) t[ty + i][tx] = src[(size_t)(n0 + ty + i) * CF + f0 + tx];
    __syncthreads();
#pragma unroll
    for (int i = 0; i < 32; i += 8) dst[(size_t)(f0 + ty + i) * NTOK + n0 + tx] = t[tx][ty + i];
}

// ---------- generic 64x64-tile bf16 MFMA GEMM: C[M][N] = A[M][K] * W[N][K]^T ----------
template<int K, int N, bool BIAS, bool RELU>
__global__ __launch_bounds__(256) void gemm_tile64(const ushort_t* __restrict__ A,
                                                   const ushort_t* __restrict__ W,
                                                   const float* __restrict__ bias,
                                                   ushort_t* __restrict__ C) {
    const int tid = threadIdx.x;
    const int wid = tid >> 6, lane = tid & 63;
    const int g = lane >> 4, r = lane & 15;
    const int row0 = blockIdx.x * 64 + wid * 16;
    const int c0 = blockIdx.y * 64;

    f32x4 acc[4] = {{0,0,0,0},{0,0,0,0},{0,0,0,0},{0,0,0,0}};
    const ushort_t* ap = A + (size_t)(row0 + r) * K + (g << 3);
    const ushort_t* wp = W + (size_t)(c0 + r) * K + (g << 3);
#pragma unroll 4
    for (int k0 = 0; k0 < K; k0 += 32) {
        const bf16x8 af = *(const bf16x8*)(ap + k0);
#pragma unroll
        for (int t = 0; t < 4; ++t) {
            const bf16x8 wf = *(const bf16x8*)(wp + (size_t)t * 16 * K + k0);
            acc[t] = __builtin_amdgcn_mfma_f32_16x16x32_bf16(af, wf, acc[t], 0, 0, 0);
        }
    }
#pragma unroll
    for (int t = 0; t < 4; ++t) {
        const int col = c0 + 16 * t + r;
        float bv = 0.f;
        if constexpr (BIAS) bv = bias[col];
#pragma unroll
        for (int q = 0; q < 4; ++q) {
            float v = acc[t][q] + bv;
            if constexpr (RELU) v = fmaxf(v, 0.f);
            C[(size_t)(row0 + 4 * g + q) * N + col] = f2bf(v);
        }
    }
}

// ---------- flash attention (bf16 MFMA) ----------
__global__ __launch_bounds__(256) void fattn_kernel(const ushort_t* __restrict__ Qb,
                                                    const ushort_t* __restrict__ Kb,
                                                    const ushort_t* __restrict__ Vt,
                                                    ushort_t* __restrict__ AOb) {
    __shared__ ushort_t plds[4][16 * 64];

    const int tid  = threadIdx.x;
    const int wid  = tid >> 6;
    const int lane = tid & 63;
    const int g    = lane >> 4;
    const int r    = lane & 15;
    const int h    = blockIdx.x >> 6;
    const int n0   = ((blockIdx.x & 63) << 6) + (wid << 4);

    ushort_t* pw = plds[wid];
    const float scale = 0.17677669529663687f;

    const bf16x8 qf = *(const bf16x8*)(Qb + ((size_t)(n0 + r) << 8) + h * HD + (g << 3));

    f32x4 acc[2] = {{0.f,0.f,0.f,0.f},{0.f,0.f,0.f,0.f}};
    float m_run[4], l_run[4];
#pragma unroll
    for (int q = 0; q < 4; ++q) { m_run[q] = -1e30f; l_run[q] = 0.f; }

    for (int m0 = 0; m0 < NTOK; m0 += 64) {
        f32x4 s[4];
#pragma unroll
        for (int t = 0; t < 4; ++t) {
            const bf16x8 kf = *(const bf16x8*)(Kb + ((size_t)(m0 + (t << 4) + r) << 8) + h * HD + (g << 3));
            s[t] = __builtin_amdgcn_mfma_f32_16x16x32_bf16(qf, kf, (f32x4){0.f,0.f,0.f,0.f}, 0, 0, 0);
        }
#pragma unroll
        for (int q = 0; q < 4; ++q) {
            float mt = fmaxf(fmaxf(s[0][q], s[1][q]), fmaxf(s[2][q], s[3][q])) * scale;
            mt = fmaxf(mt, __shfl_xor(mt, 1));
            mt = fmaxf(mt, __shfl_xor(mt, 2));
            mt = fmaxf(mt, __shfl_xor(mt, 4));
            mt = fmaxf(mt, __shfl_xor(mt, 8));
            const float mn  = fmaxf(m_run[q], mt);
            const float scl = __expf(m_run[q] - mn);
            m_run[q] = mn;
            float rs = 0.f;
#pragma unroll
            for (int t = 0; t < 4; ++t) {
                const float p = __expf(fmaf(s[t][q], scale, -mn));
                s[t][q] = p;
                rs += p;
            }
            rs += __shfl_xor(rs, 1);
            rs += __shfl_xor(rs, 2);
            rs += __shfl_xor(rs, 4);
            rs += __shfl_xor(rs, 8);
            l_run[q] = l_run[q] * scl + rs;
            acc[0][q] *= scl;
            acc[1][q] *= scl;
        }
#pragma unroll
        for (int t = 0; t < 4; ++t) {
#pragma unroll
            for (int q = 0; q < 4; ++q) {
                const int row = (g << 2) + q;
                const int bir = (r << 1) + (t << 5);
                *(ushort_t*)((char*)pw + (row << 7) + (bir ^ ((row & 7) << 4))) = f2bf(s[t][q]);
            }
        }
#pragma unroll
        for (int mc = 0; mc < 2; ++mc) {
            const int bir = (g << 4) + (mc << 6);
            const bf16x8 pf = *(const bf16x8*)((char*)pw + (r << 7) + (bir ^ ((r & 7) << 4)));
#pragma unroll
            for (int dd = 0; dd < 2; ++dd) {
                const bf16x8 vf = *(const bf16x8*)(Vt + ((size_t)(h * HD + (dd << 4) + r) << 12) + m0 + (mc << 5) + (g << 3));
                acc[dd] = __builtin_amdgcn_mfma_f32_16x16x32_bf16(pf, vf, acc[dd], 0, 0, 0);
            }
        }
    }
#pragma unroll
    for (int q = 0; q < 4; ++q) {
        const float inv = 1.f / l_run[q];
        const size_t row = (size_t)(n0 + (g << 2) + q) << 8;
        AOb[row + h * HD + r]      = f2bf(acc[0][q] * inv);
        AOb[row + h * HD + 16 + r] = f2bf(acc[1][q] * inv);
    }
}

// ---------- out-proj + residual-proj + LN1 (block = 64 rows x full 256 cols) ----------
__global__ __launch_bounds__(256) void outproj_ln1_kernel(
    const ushort_t* __restrict__ AOb, const ushort_t* __restrict__ Wo,
    const ushort_t* __restrict__ Flt, const ushort_t* __restrict__ Wres,
    const float* __restrict__ g1, const float* __restrict__ bt1,
    ushort_t* __restrict__ Xb, float* __restrict__ X32t) {
    const int tid = threadIdx.x;
    const int wid = tid >> 6, lane = tid & 63;
    const int g = lane >> 4, r = lane & 15;
    const int row0 = blockIdx.x * 64 + wid * 16;

    f32x4 acc[16];
#pragma unroll
    for (int t = 0; t < 16; ++t) acc[t] = (f32x4){0,0,0,0};

    const ushort_t* ap = AOb + (size_t)(row0 + r) * CF + (g << 3);
    const ushort_t* wp = Wo + (size_t)r * CF + (g << 3);
#pragma unroll 2
    for (int k0 = 0; k0 < CF; k0 += 32) {
        const bf16x8 af = *(const bf16x8*)(ap + k0);
#pragma unroll
        for (int t = 0; t < 16; ++t) {
            const bf16x8 wf = *(const bf16x8*)(wp + (size_t)t * 16 * CF + k0);
            acc[t] = __builtin_amdgcn_mfma_f32_16x16x32_bf16(af, wf, acc[t], 0, 0, 0);
        }
    }
    const ushort_t* ap2 = Flt + (size_t)(row0 + r) * C1 + (g << 3);
    const ushort_t* wp2 = Wres + (size_t)r * C1 + (g << 3);
#pragma unroll
    for (int k0 = 0; k0 < C1; k0 += 32) {
        const bf16x8 af = *(const bf16x8*)(ap2 + k0);
#pragma unroll
        for (int t = 0; t < 16; ++t) {
            const bf16x8 wf = *(const bf16x8*)(wp2 + (size_t)t * 16 * C1 + k0);
            acc[t] = __builtin_amdgcn_mfma_f32_16x16x32_bf16(af, wf, acc[t], 0, 0, 0);
        }
    }
    // fused LayerNorm over the 256 cols held by this wave
    float mean_[4], rstd_[4];
#pragma unroll
    for (int q = 0; q < 4; ++q) {
        float s = 0.f;
#pragma unroll
        for (int t = 0; t < 16; ++t) s += acc[t][q];
        s = rsum16(s);
        const float mn = s * (1.f / CF);
        float d2 = 0.f;
#pragma unroll
        for (int t = 0; t < 16; ++t) { const float d = acc[t][q] - mn; d2 = fmaf(d, d, d2); }
        d2 = rsum16(d2);
        mean_[q] = mn;
        rstd_[q] = rsqrtf(d2 * (1.f / CF) + EPSF);
    }
#pragma unroll
    for (int t = 0; t < 16; ++t) {
        const int col = 16 * t + r;
        const float gam = g1[col], bet = bt1[col];
        f32x4 xv;
#pragma unroll
        for (int q = 0; q < 4; ++q) xv[q] = (acc[t][q] - mean_[q]) * rstd_[q] * gam + bet;
#pragma unroll
        for (int q = 0; q < 4; ++q) Xb[(size_t)(row0 + 4 * g + q) * CF + col] = f2bf(xv[q]);
        *(f32x4*)(X32t + (size_t)col * NTOK + row0 + 4 * g) = xv;
    }
}

// ---------- FFN2 + residual + LN2 + transposed store ----------
__global__ __launch_bounds__(256) void ffn2_ln2_kernel(
    const ushort_t* __restrict__ Hb, const ushort_t* __restrict__ W2,
    const float* __restrict__ b2, const float* __restrict__ X32t,
    const float* __restrict__ g2, const float* __restrict__ bt2,
    float* __restrict__ out) {
    const int tid = threadIdx.x;
    const int wid = tid >> 6, lane = tid & 63;
    const int g = lane >> 4, r = lane & 15;
    const int row0 = blockIdx.x * 64 + wid * 16;

    f32x4 acc[16];
#pragma unroll
    for (int t = 0; t < 16; ++t) acc[t] = (f32x4){0,0,0,0};

    const ushort_t* ap = Hb + (size_t)(row0 + r) * CFF + (g << 3);
    const ushort_t* wp = W2 + (size_t)r * CFF + (g << 3);
#pragma unroll 2
    for (int k0 = 0; k0 < CFF; k0 += 32) {
        const bf16x8 af = *(const bf16x8*)(ap + k0);
#pragma unroll
        for (int t = 0; t < 16; ++t) {
            const bf16x8 wf = *(const bf16x8*)(wp + (size_t)t * 16 * CFF + k0);
            acc[t] = __builtin_amdgcn_mfma_f32_16x16x32_bf16(af, wf, acc[t], 0, 0, 0);
        }
    }
    // + b2 + residual
#pragma unroll
    for (int t = 0; t < 16; ++t) {
        const int col = 16 * t + r;
        const f32x4 res = *(const f32x4*)(X32t + (size_t)col * NTOK + row0 + 4 * g);
        const float bb = b2[col];
#pragma unroll
        for (int q = 0; q < 4; ++q) acc[t][q] += bb + res[q];
    }
    // LN2
    float mean_[4], rstd_[4];
#pragma unroll
    for (int q = 0; q < 4; ++q) {
        float s = 0.f;
#pragma unroll
        for (int t = 0; t < 16; ++t) s += acc[t][q];
        s = rsum16(s);
        const float mn = s * (1.f / CF);
        float d2 = 0.f;
#pragma unroll
        for (int t = 0; t < 16; ++t) { const float d = acc[t][q] - mn; d2 = fmaf(d, d, d2); }
        d2 = rsum16(d2);
        mean_[q] = mn;
        rstd_[q] = rsqrtf(d2 * (1.f / CF) + EPSF);
    }
#pragma unroll
    for (int t = 0; t < 16; ++t) {
        const int col = 16 * t + r;
        const float gam = g2[col], bet = bt2[col];
        f32x4 ov;
#pragma unroll
        for (int q = 0; q < 4; ++q) ov[q] = (acc[t][q] - mean_[q]) * rstd_[q] * gam + bet;
        *(f32x4*)(out + (size_t)col * NTOK + row0 + 4 * g) = ov;
    }
}

extern "C" void kernel_launch(void* const* d_in, const int* in_sizes, int n_in,
                              void* d_out, int out_size, void* d_ws, size_t ws_size,
                              hipStream_t stream) {
    const float* F_lidar = (const float*)d_in[0];
    const float* F_cam   = (const float*)d_in[1];
    const float* Wq      = (const float*)d_in[2];
    const float* Wk      = (const float*)d_in[3];
    const float* Wv      = (const float*)d_in[4];
    const float* Wo      = (const float*)d_in[5];
    const float* Wres    = (const float*)d_in[6];
    const float* ln1_g   = (const float*)d_in[7];
    const float* ln1_b   = (const float*)d_in[8];
    const float* ln2_g   = (const float*)d_in[9];
    const float* ln2_b   = (const float*)d_in[10];
    const float* W1      = (const float*)d_in[11];
    const float* b1      = (const float*)d_in[12];
    const float* W2      = (const float*)d_in[13];
    const float* b2      = (const float*)d_in[14];
    float* out = (float*)d_out;
    char* ws = (char*)d_ws;

    const size_t KB = 1024, MB = 1024 * 1024;
    ushort_t* Wq_b   = (ushort_t*)(ws + 0);
    ushort_t* Wk_b   = (ushort_t*)(ws + 32 * KB);
    ushort_t* Wv_b   = (ushort_t*)(ws + 160 * KB);
    ushort_t* Wo_b   = (ushort_t*)(ws + 288 * KB);
    ushort_t* Wres_b = (ushort_t*)(ws + 416 * KB);
    ushort_t* W1_b   = (ushort_t*)(ws + 448 * KB);
    ushort_t* W2_b   = (ushort_t*)(ws + 960 * KB);
    ushort_t* Flt    = (ushort_t*)(ws + 1536 * KB);   // bf16 [4096][64]   512K
    ushort_t* Fct    = (ushort_t*)(ws + 2 * MB);      // bf16 [4096][256]  2M
    ushort_t* Qb     = (ushort_t*)(ws + 4 * MB);      // 2M
    ushort_t* Kb     = (ushort_t*)(ws + 6 * MB);      // 2M
    ushort_t* Vb     = (ushort_t*)(ws + 8 * MB);      // 2M
    ushort_t* Vt     = (ushort_t*)(ws + 10 * MB);     // 2M
    ushort_t* AOb    = (ushort_t*)(ws + 12 * MB);     // 2M
    ushort_t* Xb     = (ushort_t*)(ws + 14 * MB);     // 2M
    float*    X32t   = (float*)(ws + 16 * MB);        // fp32 [256][4096]  4M
    ushort_t* Hb     = (ushort_t*)(ws + 4 * MB);      // bf16 [4096][1024] 8M (reuses Qb..Vt)

    convert_weights_kernel<<<736, 256, 0, stream>>>(Wq, Wk, Wv, Wo, Wres, W1, W2,
                                                    Wq_b, Wk_b, Wv_b, Wo_b, Wres_b, W1_b, W2_b);
    tr_f32_kernel<C1><<<dim3(C1 / 32, NTOK / 32), 256, 0, stream>>>(F_lidar, Flt);
    tr_f32_kernel<C2><<<dim3(C2 / 32, NTOK / 32), 256, 0, stream>>>(F_cam, Fct);
    gemm_tile64<C1, CF, false, false><<<dim3(NTOK / 64, CF / 64), 256, 0, stream>>>(Flt, Wq_b, nullptr, Qb);
    gemm_tile64<C2, CF, false, false><<<dim3(NTOK / 64, CF / 64), 256, 0, stream>>>(Fct, Wk_b, nullptr, Kb);
    gemm_tile64<C2, CF, false, false><<<dim3(NTOK / 64, CF / 64), 256, 0, stream>>>(Fct, Wv_b, nullptr, Vb);
    tr_bf16_kernel<<<dim3(NTOK / 32, CF / 32), 256, 0, stream>>>(Vb, Vt);
    fattn_kernel<<<NH * (NTOK / 64), 256, 0, stream>>>(Qb, Kb, Vt, AOb);
    outproj_ln1_kernel<<<NTOK / 64, 256, 0, stream>>>(AOb, Wo_b, Flt, Wres_b, ln1_g, ln1_b, Xb, X32t);
    gemm_tile64<CF, CFF, true, true><<<dim3(NTOK / 64, CFF / 64), 256, 0, stream>>>(Xb, W1_b, b1, Hb);
    ffn2_ln2_kernel<<<NTOK / 64, 256, 0, stream>>>(Hb, W2_b, b2, X32t, ln2_g, ln2_b, out);
}